// Round 1
// baseline (226.001 us; speedup 1.0000x reference)
//
#include <hip/hip_runtime.h>
#include <hip/hip_bf16.h>

// out[r][c] = x[r][c] * weight[c] + bias[c]
// x: (8192, 4096) f32, weight/bias: (4096,) f32, out: (8192, 4096) f32.
// Memory-bound streaming: float4 per thread, col4 = idx & 1023.

#define IN_SIZE   4096
#define COLS4     (IN_SIZE / 4)   // 1024

__global__ __launch_bounds__(256) void diag_linear_kernel(
    const float4* __restrict__ x,
    const float4* __restrict__ w,
    const float4* __restrict__ b,
    float4* __restrict__ out,
    int n4)  // total float4 elements
{
    int idx = blockIdx.x * blockDim.x + threadIdx.x;
    if (idx >= n4) return;

    int c4 = idx & (COLS4 - 1);

    float4 xv = x[idx];
    float4 wv = w[c4];
    float4 bv = b[c4];

    float4 o;
    o.x = fmaf(xv.x, wv.x, bv.x);
    o.y = fmaf(xv.y, wv.y, bv.y);
    o.z = fmaf(xv.z, wv.z, bv.z);
    o.w = fmaf(xv.w, wv.w, bv.w);

    out[idx] = o;
}

extern "C" void kernel_launch(void* const* d_in, const int* in_sizes, int n_in,
                              void* d_out, int out_size, void* d_ws, size_t ws_size,
                              hipStream_t stream) {
    const float4* x = (const float4*)d_in[0];
    const float4* w = (const float4*)d_in[1];
    const float4* b = (const float4*)d_in[2];
    float4* out = (float4*)d_out;

    int n4 = out_size / 4;  // 8192*4096/4 = 8388608
    int block = 256;
    int grid = (n4 + block - 1) / block;

    diag_linear_kernel<<<grid, block, 0, stream>>>(x, w, b, out, n4);
}